// Round 4
// baseline (128.567 us; speedup 1.0000x reference)
//
#include <hip/hip_runtime.h>

#define D 256
#define H 8
#define B 32
#define S 1024
#define SCH 32      // s-chunks per batch
#define SCS 32      // s per chunk

// workspace layout (float offsets)
#define OFF_QK     0                       // [H][D]               2048
#define OFF_SB     2048                    // [H]                  8
#define OFF_ML     2056                    // [B][SCH][H] float2   16384 floats
#define OFF_XWP    18440                   // [B][SCH][H][D]       2097152
#define OFF_POOLED 2115592                 // [B][H*D]             65536
// total ~8.7 MB

// qk[h][k] = sum_d Wk[k, h*D+d]*q[h][d]; sb[h] = bk_h . q[h]; out[b]=bo.
// grid = H*32 = 256 blocks; thread = (kl = t>>5: 8 k's) x (dq = t&31: 8 d's)
__global__ void k_prep(const float* __restrict__ Wk, const float* __restrict__ bk,
                       const float* __restrict__ query, const float* __restrict__ bo,
                       float* __restrict__ qk, float* __restrict__ sb,
                       float* __restrict__ out) {
    __shared__ float red[256];
    const int h  = blockIdx.x >> 5;
    const int kc = blockIdx.x & 31;
    const int t  = threadIdx.x;
    const int kl = t >> 5;
    const int dq = t & 31;
    const int k  = kc * 8 + kl;
    const int d0 = dq * 8;
    const float* wrow = Wk + (size_t)k * (D * H) + h * D + d0;
    const float* qrow = query + h * D + d0;
    const float4 w0 = *(const float4*)(wrow);
    const float4 w1 = *(const float4*)(wrow + 4);
    const float4 q0 = *(const float4*)(qrow);
    const float4 q1 = *(const float4*)(qrow + 4);
    float acc = w0.x * q0.x + w0.y * q0.y + w0.z * q0.z + w0.w * q0.w
              + w1.x * q1.x + w1.y * q1.y + w1.z * q1.z + w1.w * q1.w;
    #pragma unroll
    for (int msk = 1; msk < 32; msk <<= 1) acc += __shfl_xor(acc, msk);
    if (dq == 0) qk[h * D + k] = acc;
    if (kc == 0) {                          // block-uniform
        red[t] = bk[h * D + t] * query[h * D + t];
        __syncthreads();
        for (int st = 128; st > 0; st >>= 1) {
            if (t < st) red[t] += red[t + st];
            __syncthreads();
        }
        if (t == 0) sb[h] = red[0];
    }
    if (h == 0) out[(size_t)kc * D + t] = bo[t];   // out init, b = kc
}

// One (b, chunk of 32 s): scores -> chunk softmax (m,l saved) -> unnormalized
// weighted sum. grid = B*SCH = 1024 blocks (4/CU), 256 thr.
__global__ void k_fused(const float* __restrict__ x, const float* __restrict__ qk,
                        const float* __restrict__ sb, float* __restrict__ xwp,
                        float2* __restrict__ mlbuf) {
    const int b  = blockIdx.x >> 5;
    const int c  = blockIdx.x & 31;
    const int s0 = c * SCS;
    const int t  = threadIdx.x;
    __shared__ float qkL[H * D];            // 8 KB
    __shared__ float sbL[H];
    __shared__ float sc[SCS][H];            // 1 KB
    {   // stage qk (L2-hot) vectorized
        float4* q4 = (float4*)qkL;
        q4[t]       = ((const float4*)qk)[t];
        q4[t + 256] = ((const float4*)qk)[t + 256];
        if (t < H) sbL[t] = sb[t];
    }
    __syncthreads();

    // pass A: thread = (sl = t>>3) x (dq = t&7, 32 d's). XOR-staggered q reads:
    // for fixed j0, lanes dq=0..7 hit banks 4*((j0+dq)&7) -> conflict-free.
    {
        const int sl = t >> 3;
        const int dq = t & 7;
        const int d0 = dq * 32;
        const float* xrow = x + ((size_t)(b * S + s0 + sl)) * D + d0;
        float4 xr[8];
        #pragma unroll
        for (int j0 = 0; j0 < 8; j0++) {
            const int j = (j0 + dq) & 7;
            xr[j0] = *(const float4*)(xrow + j * 4);
        }
        float accA[H] = {};
        #pragma unroll
        for (int j0 = 0; j0 < 8; j0++) {
            const int j = (j0 + dq) & 7;
            const float4 xv = xr[j0];
            #pragma unroll
            for (int hh = 0; hh < H; hh++) {
                const float4 qv = *(const float4*)(&qkL[hh * D + d0 + j * 4]);
                accA[hh] += xv.x * qv.x + xv.y * qv.y + xv.z * qv.z + xv.w * qv.w;
            }
        }
        #pragma unroll
        for (int hh = 0; hh < H; hh++) {
            accA[hh] += __shfl_xor(accA[hh], 1);
            accA[hh] += __shfl_xor(accA[hh], 2);
            accA[hh] += __shfl_xor(accA[hh], 4);
        }
        if (dq == 0) {
            #pragma unroll
            for (int hh = 0; hh < H; hh++)
                sc[sl][hh] = accA[hh] + sbL[hh];
        }
    }
    __syncthreads();

    // chunk softmax over 32 s per head: thread = (hh = t>>5) x (u = t&31)
    {
        const int hh = t >> 5;
        const int u  = t & 31;
        const float v = sc[u][hh];
        float m = v;
        #pragma unroll
        for (int msk = 1; msk < 32; msk <<= 1) m = fmaxf(m, __shfl_xor(m, msk));
        const float e = __expf(v - m);
        float sum = e;
        #pragma unroll
        for (int msk = 1; msk < 32; msk <<= 1) sum += __shfl_xor(sum, msk);
        sc[u][hh] = e;
        if (u == 0) mlbuf[((size_t)(b * SCH + c)) * H + hh] = make_float2(m, sum);
    }
    __syncthreads();

    // pass B: thread = d; x re-read (L1/L2-hot), p broadcast from LDS
    {
        float acc2[H] = {};
        const float* xp = x + ((size_t)(b * S + s0)) * D + t;
        #pragma unroll 4
        for (int s = 0; s < SCS; s++) {
            const float xv = xp[(size_t)s * D];
            const float4 pa = *(const float4*)(&sc[s][0]);
            const float4 pb = *(const float4*)(&sc[s][4]);
            acc2[0] += pa.x * xv; acc2[1] += pa.y * xv;
            acc2[2] += pa.z * xv; acc2[3] += pa.w * xv;
            acc2[4] += pb.x * xv; acc2[5] += pb.y * xv;
            acc2[6] += pb.z * xv; acc2[7] += pb.w * xv;
        }
        #pragma unroll
        for (int hh = 0; hh < H; hh++)
            xwp[(((size_t)(b * SCH + c)) * H + hh) * D + t] = acc2[hh];
    }
}

// combine chunks (rescale by exp(m_c-M)/L) + pooled GEMV vs Wv.
// grid = B*H = 256 blocks, 256 thr (t = j)
__global__ void k_pooled(const float* __restrict__ xwp, const float2* __restrict__ mlbuf,
                         const float* __restrict__ Wv, const float* __restrict__ bv,
                         float* __restrict__ pooled) {
    const int bh = blockIdx.x;
    const int b = bh >> 3, h = bh & 7;
    const int j = threadIdx.x;
    __shared__ float xwL[D];
    __shared__ float scaleL[SCH];
    __shared__ float2 mlL[SCH];
    if (j < SCH) mlL[j] = mlbuf[((size_t)(b * SCH + j)) * H + h];
    __syncthreads();
    if (j == 0) {
        float M = -1e30f;
        for (int cc = 0; cc < SCH; cc++) M = fmaxf(M, mlL[cc].x);
        float L = 0.f;
        for (int cc = 0; cc < SCH; cc++) L += mlL[cc].y * __expf(mlL[cc].x - M);
        const float invL = 1.f / L;
        for (int cc = 0; cc < SCH; cc++) scaleL[cc] = __expf(mlL[cc].x - M) * invL;
    }
    __syncthreads();
    float acc = 0.f;
    #pragma unroll
    for (int cc = 0; cc < SCH; cc++)
        acc += xwp[(((size_t)(b * SCH + cc)) * H + h) * D + j] * scaleL[cc];
    xwL[j] = acc;
    __syncthreads();
    const float* wcol = Wv + h * D + j;     // row stride D*H
    float a2 = 0.f;
    #pragma unroll 8
    for (int d = 0; d < D; d++)
        a2 += xwL[d] * wcol[(size_t)d * (D * H)];
    pooled[(size_t)b * (D * H) + h * D + j] = a2 + bv[h * D + j];
}

// out[b,j] += sum_{k in chunk} pooled[b,k]*Wo[k,j]; out pre-initialized to bo.
// grid = B*8 = 256 blocks, 256 thr (t = j)
__global__ void k_out(const float* __restrict__ pooled, const float* __restrict__ Wo,
                      float* __restrict__ out) {
    const int b  = blockIdx.x >> 3;
    const int kc = blockIdx.x & 7;
    const int j  = threadIdx.x;
    __shared__ float pL[256];
    pL[j] = pooled[(size_t)b * (D * H) + kc * 256 + j];
    __syncthreads();
    const float* wp = Wo + (size_t)(kc * 256) * D + j;
    float acc = 0.f;
    #pragma unroll 8
    for (int cc = 0; cc < 256; cc++)
        acc += pL[cc] * wp[(size_t)cc * D];
    atomicAdd(out + (size_t)b * D + j, acc);
}

extern "C" void kernel_launch(void* const* d_in, const int* in_sizes, int n_in,
                              void* d_out, int out_size, void* d_ws, size_t ws_size,
                              hipStream_t stream) {
    const float* x     = (const float*)d_in[0];
    const float* Wk    = (const float*)d_in[1];
    const float* bk    = (const float*)d_in[2];
    const float* Wv    = (const float*)d_in[3];
    const float* bv    = (const float*)d_in[4];
    const float* query = (const float*)d_in[5];
    const float* Wo    = (const float*)d_in[6];
    const float* bo    = (const float*)d_in[7];
    float* out = (float*)d_out;
    float* ws  = (float*)d_ws;

    float*  qk     = ws + OFF_QK;
    float*  sb     = ws + OFF_SB;
    float2* mlbuf  = (float2*)(ws + OFF_ML);
    float*  xwp    = ws + OFF_XWP;
    float*  pooled = ws + OFF_POOLED;

    k_prep<<<dim3(H * 32), dim3(256), 0, stream>>>(Wk, bk, query, bo, qk, sb, out);
    k_fused<<<dim3(B * SCH), dim3(256), 0, stream>>>(x, qk, sb, xwp, mlbuf);
    k_pooled<<<dim3(B * H), dim3(256), 0, stream>>>(xwp, mlbuf, Wv, bv, pooled);
    k_out<<<dim3(B * 8), dim3(256), 0, stream>>>(pooled, Wo, out);
}

// Round 5
// 115.111 us; speedup vs baseline: 1.1169x; 1.1169x over previous
//
#include <hip/hip_runtime.h>

#define D 256
#define H 8
#define B 32
#define S 1024
#define SCH 16      // s-chunks per batch
#define SCS 64      // s per chunk

// workspace layout (float offsets)
#define OFF_QK     0                       // [H][D]               2048
#define OFF_SB     2048                    // [H]                  8
#define OFF_ML     2056                    // [B][SCH][H] float2   8192 floats
#define OFF_XWP    10248                   // [B][SCH][H][D]       1048576
#define OFF_POOLED 1058824                 // [B][H*D]             65536
// total ~4.5 MB

// qk[h][k] = sum_d Wk[k,h*D+d]*q[h][d]; sb[h] = bk_h . q[h];
// also inits: out[b=kc]=bo, pooled[b=kc, h*D+t]=bv[h*D+t].
// grid = H*32 = 256 blocks; thread = (kl = t>>5: 8 k's) x (dq = t&31: 8 d's)
__global__ void __launch_bounds__(256) k_prep(
        const float* __restrict__ Wk, const float* __restrict__ bk,
        const float* __restrict__ query, const float* __restrict__ bo,
        const float* __restrict__ bv,
        float* __restrict__ qk, float* __restrict__ sb,
        float* __restrict__ out, float* __restrict__ pooled) {
    __shared__ float red[256];
    const int h  = blockIdx.x >> 5;
    const int kc = blockIdx.x & 31;
    const int t  = threadIdx.x;
    const int kl = t >> 5;
    const int dq = t & 31;
    const int k  = kc * 8 + kl;
    const int d0 = dq * 8;
    const float* wrow = Wk + (size_t)k * (D * H) + h * D + d0;
    const float* qrow = query + h * D + d0;
    const float4 w0 = *(const float4*)(wrow);
    const float4 w1 = *(const float4*)(wrow + 4);
    const float4 q0 = *(const float4*)(qrow);
    const float4 q1 = *(const float4*)(qrow + 4);
    float acc = w0.x * q0.x + w0.y * q0.y + w0.z * q0.z + w0.w * q0.w
              + w1.x * q1.x + w1.y * q1.y + w1.z * q1.z + w1.w * q1.w;
    #pragma unroll
    for (int msk = 1; msk < 32; msk <<= 1) acc += __shfl_xor(acc, msk);
    if (dq == 0) qk[h * D + k] = acc;
    if (kc == 0) {                          // block-uniform
        red[t] = bk[h * D + t] * query[h * D + t];
        __syncthreads();
        for (int st = 128; st > 0; st >>= 1) {
            if (t < st) red[t] += red[t + st];
            __syncthreads();
        }
        if (t == 0) sb[h] = red[0];
    }
    pooled[(size_t)kc * (D * H) + h * D + t] = bv[h * D + t];
    if (h == 0) out[(size_t)kc * D + t] = bo[t];
}

// One (b, chunk of 64 s): scores -> chunk softmax (m,l saved) -> unnormalized
// weighted sum. grid = B*SCH = 512 blocks, 256 thr.
__global__ void __launch_bounds__(256) k_fused(
        const float* __restrict__ x, const float* __restrict__ qk,
        const float* __restrict__ sb, float* __restrict__ xwp,
        float2* __restrict__ mlbuf) {
    const int b  = blockIdx.x >> 4;
    const int c  = blockIdx.x & 15;
    const int s0 = c * SCS;
    const int t  = threadIdx.x;
    __shared__ float qkL[H * D];            // 8 KB
    __shared__ float sbL[H];
    __shared__ float sc[SCS][H];            // 2 KB
    {
        float4* q4 = (float4*)qkL;
        q4[t]       = ((const float4*)qk)[t];
        q4[t + 256] = ((const float4*)qk)[t + 256];
        if (t < H) sbL[t] = sb[t];
    }
    __syncthreads();

    // pass A: thread = (sl = t>>2: 64 s) x (dq = t&3: 64 d's).
    // XOR-staggered j: for fixed j0, lanes dq=0..3 read qkL at d = dq*64 + ((j0+dq*4)&15)*4
    // -> distinct bank groups, conflict-free.
    {
        const int sl = t >> 2;
        const int dq = t & 3;
        const int d0 = dq * 64;
        const float* xrow = x + ((size_t)(b * S + s0 + sl)) * D + d0;
        float accA[H] = {};
        #pragma unroll
        for (int j0 = 0; j0 < 16; j0++) {
            const int j = (j0 + dq * 4) & 15;
            const float4 xv = *(const float4*)(xrow + j * 4);
            #pragma unroll
            for (int hh = 0; hh < H; hh++) {
                const float4 qv = *(const float4*)(&qkL[hh * D + d0 + j * 4]);
                accA[hh] += xv.x * qv.x + xv.y * qv.y + xv.z * qv.z + xv.w * qv.w;
            }
        }
        #pragma unroll
        for (int hh = 0; hh < H; hh++) {
            accA[hh] += __shfl_xor(accA[hh], 1);
            accA[hh] += __shfl_xor(accA[hh], 2);
        }
        if (dq == 0) {
            #pragma unroll
            for (int hh = 0; hh < H; hh++)
                sc[sl][hh] = accA[hh] + sbL[hh];
        }
    }
    __syncthreads();

    // chunk softmax over 64 s per head: thread = (hh = t>>5) x (u = t&31)
    {
        const int hh = t >> 5;
        const int u  = t & 31;
        const float v0 = sc[u][hh], v1 = sc[u + 32][hh];
        float m = fmaxf(v0, v1);
        #pragma unroll
        for (int msk = 1; msk < 32; msk <<= 1) m = fmaxf(m, __shfl_xor(m, msk));
        const float e0 = __expf(v0 - m), e1 = __expf(v1 - m);
        float sum = e0 + e1;
        #pragma unroll
        for (int msk = 1; msk < 32; msk <<= 1) sum += __shfl_xor(sum, msk);
        sc[u][hh] = e0;
        sc[u + 32][hh] = e1;
        if (u == 0) mlbuf[((size_t)(b * SCH + c)) * H + hh] = make_float2(m, sum);
    }
    __syncthreads();

    // pass B: thread = d (t); x re-read from L1/L2, p broadcast from LDS.
    {
        float acc2[H] = {};
        const float* xp = x + ((size_t)(b * S + s0)) * D + t;
        #pragma unroll 4
        for (int s = 0; s < SCS; s++) {
            const float xv = xp[(size_t)s * D];
            const float4 pa = *(const float4*)(&sc[s][0]);
            const float4 pb = *(const float4*)(&sc[s][4]);
            acc2[0] += pa.x * xv; acc2[1] += pa.y * xv;
            acc2[2] += pa.z * xv; acc2[3] += pa.w * xv;
            acc2[4] += pb.x * xv; acc2[5] += pb.y * xv;
            acc2[6] += pb.z * xv; acc2[7] += pb.w * xv;
        }
        #pragma unroll
        for (int hh = 0; hh < H; hh++)
            xwp[(((size_t)(b * SCH + c)) * H + hh) * D + t] = acc2[hh];
    }
}

// combine chunks (rescale by exp(m_c-M)/L) + pooled GEMV vs Wv, split-K over d.
// grid = B*H*2 = 512 blocks, 256 thr; atomicAdd into bv-initialized pooled.
__global__ void __launch_bounds__(256) k_pooled(
        const float* __restrict__ xwp, const float2* __restrict__ mlbuf,
        const float* __restrict__ Wv, float* __restrict__ pooled) {
    const int blk = blockIdx.x;
    const int bh  = blk >> 1;
    const int dh  = blk & 1;                // d-half
    const int b = bh >> 3, h = bh & 7;
    const int j = threadIdx.x;
    __shared__ float xwL[D / 2];
    __shared__ float scaleL[SCH];
    __shared__ float2 mlL[SCH];
    if (j < SCH) mlL[j] = mlbuf[((size_t)(b * SCH + j)) * H + h];
    __syncthreads();
    if (j == 0) {
        float M = -1e30f;
        for (int cc = 0; cc < SCH; cc++) M = fmaxf(M, mlL[cc].x);
        float L = 0.f;
        for (int cc = 0; cc < SCH; cc++) L += mlL[cc].y * __expf(mlL[cc].x - M);
        const float invL = 1.f / L;
        for (int cc = 0; cc < SCH; cc++) scaleL[cc] = __expf(mlL[cc].x - M) * invL;
    }
    __syncthreads();
    if (j < D / 2) {
        const int d = dh * (D / 2) + j;
        float acc = 0.f;
        #pragma unroll
        for (int cc = 0; cc < SCH; cc++)
            acc += xwp[(((size_t)(b * SCH + cc)) * H + h) * D + d] * scaleL[cc];
        xwL[j] = acc;
    }
    __syncthreads();
    const float* wcol = Wv + (size_t)(dh * (D / 2)) * (D * H) + h * D + j;
    float a2 = 0.f;
    #pragma unroll 8
    for (int d = 0; d < D / 2; d++)
        a2 += xwL[d] * wcol[(size_t)d * (D * H)];
    atomicAdd(pooled + (size_t)b * (D * H) + h * D + j, a2);
}

// out[b,j] += sum_{k in chunk} pooled[b,k]*Wo[k,j]; out pre-initialized to bo.
// grid = B*16 = 512 blocks (16 k-chunks of 128), 256 thr (t = j)
__global__ void __launch_bounds__(256) k_out(
        const float* __restrict__ pooled, const float* __restrict__ Wo,
        float* __restrict__ out) {
    const int b  = blockIdx.x >> 4;
    const int kc = blockIdx.x & 15;
    const int j  = threadIdx.x;
    __shared__ float pL[128];
    if (j < 128) pL[j] = pooled[(size_t)b * (D * H) + kc * 128 + j];
    __syncthreads();
    const float* wp = Wo + (size_t)(kc * 128) * D + j;
    float acc = 0.f;
    #pragma unroll 8
    for (int cc = 0; cc < 128; cc++)
        acc += pL[cc] * wp[(size_t)cc * D];
    atomicAdd(out + (size_t)b * D + j, acc);
}

extern "C" void kernel_launch(void* const* d_in, const int* in_sizes, int n_in,
                              void* d_out, int out_size, void* d_ws, size_t ws_size,
                              hipStream_t stream) {
    const float* x     = (const float*)d_in[0];
    const float* Wk    = (const float*)d_in[1];
    const float* bk    = (const float*)d_in[2];
    const float* Wv    = (const float*)d_in[3];
    const float* bv    = (const float*)d_in[4];
    const float* query = (const float*)d_in[5];
    const float* Wo    = (const float*)d_in[6];
    const float* bo    = (const float*)d_in[7];
    float* out = (float*)d_out;
    float* ws  = (float*)d_ws;

    float*  qk     = ws + OFF_QK;
    float*  sb     = ws + OFF_SB;
    float2* mlbuf  = (float2*)(ws + OFF_ML);
    float*  xwp    = ws + OFF_XWP;
    float*  pooled = ws + OFF_POOLED;

    k_prep<<<dim3(H * 32), dim3(256), 0, stream>>>(Wk, bk, query, bo, bv, qk, sb, out, pooled);
    k_fused<<<dim3(B * SCH), dim3(256), 0, stream>>>(x, qk, sb, xwp, mlbuf);
    k_pooled<<<dim3(B * H * 2), dim3(256), 0, stream>>>(xwp, mlbuf, Wv, pooled);
    k_out<<<dim3(B * 16), dim3(256), 0, stream>>>(pooled, Wo, out);
}